// Round 1
// baseline (5235.989 us; speedup 1.0000x reference)
//
#include <hip/hip_runtime.h>
#include <hip/hip_bf16.h>

// TreeDecoder: B=4096, MLP 16->64->256->1024->4096 (leaky), reshape (B,64,64),
// then 3x [BinaryTreeConv -> TreeLayerNorm -> LeakyReLU], out (B,512,64) fp32.

__device__ __forceinline__ float leaky(float v) { return v > 0.0f ? v : 0.01f * v; }

__device__ __forceinline__ float cvt_load(const float v) { return v; }
__device__ __forceinline__ float cvt_load(const __hip_bfloat16 v) { return __bfloat162float(v); }
__device__ __forceinline__ void cvt_store(float* p, float v) { *p = v; }
__device__ __forceinline__ void cvt_store(__hip_bfloat16* p, float v) { *p = __float2bfloat16(v); }

// C[m,n] = leaky(sum_k A[m,k]*W[n,k] + bias[n]); M,N multiples of 64, K multiple of 16.
__global__ __launch_bounds__(256) void gemm_leaky_kernel(
    const float* __restrict__ A, const float* __restrict__ W,
    const float* __restrict__ bias, float* __restrict__ Cmat,
    int M, int N, int K)
{
    __shared__ float As[16][68];   // As[kk][mm], +4 pad: b128 reads, conflict-light stores
    __shared__ float Ws[16][68];
    const int tid = threadIdx.x;
    const int tx = tid & 15, ty = tid >> 4;
    const int n0 = blockIdx.x * 64, m0 = blockIdx.y * 64;
    const int row = tid >> 2, kq = tid & 3;   // 64 rows x 4 float4-slots per 16-k tile
    float acc[4][4] = {};

    for (int k0 = 0; k0 < K; k0 += 16) {
        const float4 a = *(const float4*)&A[(size_t)(m0 + row) * K + k0 + kq * 4];
        const float4 w = *(const float4*)&W[(size_t)(n0 + row) * K + k0 + kq * 4];
        __syncthreads();
        As[kq*4+0][row] = a.x; As[kq*4+1][row] = a.y; As[kq*4+2][row] = a.z; As[kq*4+3][row] = a.w;
        Ws[kq*4+0][row] = w.x; Ws[kq*4+1][row] = w.y; Ws[kq*4+2][row] = w.z; Ws[kq*4+3][row] = w.w;
        __syncthreads();
        #pragma unroll
        for (int kk = 0; kk < 16; ++kk) {
            float avv[4], wvv[4];
            *(float4*)avv = *(const float4*)&As[kk][ty * 4];
            *(float4*)wvv = *(const float4*)&Ws[kk][tx * 4];
            #pragma unroll
            for (int i = 0; i < 4; ++i)
                #pragma unroll
                for (int j = 0; j < 4; ++j)
                    acc[i][j] = fmaf(avv[i], wvv[j], acc[i][j]);
        }
    }
    #pragma unroll
    for (int i = 0; i < 4; ++i) {
        const int m = m0 + ty * 4 + i;
        float4 r;
        r.x = leaky(acc[i][0] + bias[n0 + tx*4 + 0]);
        r.y = leaky(acc[i][1] + bias[n0 + tx*4 + 1]);
        r.z = leaky(acc[i][2] + bias[n0 + tx*4 + 2]);
        r.w = leaky(acc[i][3] + bias[n0 + tx*4 + 3]);
        *(float4*)&Cmat[(size_t)m * N + n0 + tx * 4] = r;
    }
}

// BinaryTreeConv: out[b,o,1+n] = sum_{c,k} x[b,c,idx[b,3n+k]] * W[o,c,k] + bias[o]
// One block per (o-tile of 64, sample). Also accumulates per-sample sum/sumsq into stats.
template <int C, int O, typename Tin, typename Tout>
__global__ __launch_bounds__(256) void conv_kernel(
    const Tin* __restrict__ x, const int* __restrict__ idx,
    const float* __restrict__ W, const float* __restrict__ bias,
    Tout* __restrict__ raw, float* __restrict__ stats)
{
    constexpr int K = 3 * C;
    __shared__ float Wt[16][68];   // Wt[kk][oo]
    __shared__ float gt[16][68];   // gt[kk][nn]  (nn=63 zero-padded)
    __shared__ int   idxl[192];
    __shared__ float red[8];

    const int tid = threadIdx.x;
    const int b  = blockIdx.y;
    const int o0 = blockIdx.x * 64;
    if (tid < 189) idxl[tid] = idx[b * 189 + tid];
    const int tx = tid & 15, ty = tid >> 4;
    const int row = tid >> 2, kq = tid & 3;
    const int kkg = tid >> 4;            // this thread's kk row for the gather
    const int nnb = (tid & 15) * 4;      // first nn it fills
    const Tin* xb = x + (size_t)b * C * 64;
    float acc[4][4] = {};
    __syncthreads();   // idxl ready

    for (int k0 = 0; k0 < K; k0 += 16) {
        const float4 w = *(const float4*)&W[(size_t)(o0 + row) * K + k0 + kq * 4];
        float gv[4];
        {
            const int kg = k0 + kkg;
            const int c  = kg / 3;
            const int r  = kg - c * 3;
            #pragma unroll
            for (int q = 0; q < 4; ++q) {
                const int nn = nnb + q;
                gv[q] = (nn < 63) ? cvt_load(xb[c * 64 + idxl[nn * 3 + r]]) : 0.0f;
            }
        }
        __syncthreads();
        Wt[kq*4+0][row] = w.x; Wt[kq*4+1][row] = w.y; Wt[kq*4+2][row] = w.z; Wt[kq*4+3][row] = w.w;
        #pragma unroll
        for (int q = 0; q < 4; ++q) gt[kkg][nnb + q] = gv[q];
        __syncthreads();
        #pragma unroll
        for (int kk = 0; kk < 16; ++kk) {
            float avv[4], gvv[4];
            *(float4*)avv = *(const float4*)&Wt[kk][ty * 4];
            *(float4*)gvv = *(const float4*)&gt[kk][tx * 4];
            #pragma unroll
            for (int i = 0; i < 4; ++i)
                #pragma unroll
                for (int j = 0; j < 4; ++j)
                    acc[i][j] = fmaf(avv[i], gvv[j], acc[i][j]);
        }
    }

    float s1 = 0.0f, s2 = 0.0f;
    #pragma unroll
    for (int i = 0; i < 4; ++i) {
        const int o = o0 + ty * 4 + i;
        const float bo = bias[o];
        #pragma unroll
        for (int j = 0; j < 4; ++j) {
            const int n = tx * 4 + j;
            if (n < 63) {
                const float v = acc[i][j] + bo;
                cvt_store(&raw[((size_t)b * O + o) * 64 + n + 1], v);
                s1 += v;
                s2 += v * v;
            }
        }
    }
    #pragma unroll
    for (int off = 32; off > 0; off >>= 1) {
        s1 += __shfl_down(s1, off, 64);
        s2 += __shfl_down(s2, off, 64);
    }
    const int lane = tid & 63, wid = tid >> 6;
    if (lane == 0) { red[wid * 2] = s1; red[wid * 2 + 1] = s2; }
    __syncthreads();
    if (tid == 0) {
        atomicAdd(&stats[b * 2 + 0], red[0] + red[2] + red[4] + red[6]);
        atomicAdd(&stats[b * 2 + 1], red[1] + red[3] + red[5] + red[7]);
    }
}

// In-place LayerNorm (+ zero slot 0) + leaky. Matches ref: (x-mean)/(sqrt(var_unbiased)+1e-5)
template <typename T>
__global__ __launch_bounds__(256) void ln_leaky_kernel(
    T* buf, const float* __restrict__ stats, int O64, long long total)
{
    const long long e = (long long)blockIdx.x * 256 + threadIdx.x;
    if (e >= total) return;
    const int n = (int)(e & 63);
    const int b = (int)(e / O64);
    const float s1 = stats[b * 2], s2 = stats[b * 2 + 1];
    const float cnt = (float)O64;
    const float mean = s1 / cnt;
    float var = (s2 - s1 * mean) / (cnt - 1.0f);
    var = fmaxf(var, 0.0f);
    const float inv = 1.0f / (sqrtf(var) + 1e-5f);
    const float v = (n == 0) ? 0.0f : cvt_load(buf[e]);
    cvt_store(&buf[e], leaky((v - mean) * inv));
}

__global__ __launch_bounds__(256) void zero_kernel(float* p, int n)
{
    const int i = blockIdx.x * 256 + threadIdx.x;
    if (i < n) p[i] = 0.0f;
}

extern "C" void kernel_launch(void* const* d_in, const int* in_sizes, int n_in,
                              void* d_out, int out_size, void* d_ws, size_t ws_size,
                              hipStream_t stream)
{
    const int B = 4096;
    const float* trees = (const float*)d_in[0];
    const int*   indexes = (const int*)d_in[1];
    const float* W1 = (const float*)d_in[2];
    const float* b1 = (const float*)d_in[3];
    const float* W2 = (const float*)d_in[4];
    const float* b2 = (const float*)d_in[5];
    const float* W3 = (const float*)d_in[6];
    const float* b3 = (const float*)d_in[7];
    const float* W4 = (const float*)d_in[8];
    const float* b4 = (const float*)d_in[9];
    const float* cw1 = (const float*)d_in[10];
    const float* cb1 = (const float*)d_in[11];
    const float* cw2 = (const float*)d_in[12];
    const float* cb2 = (const float*)d_in[13];
    const float* cw3 = (const float*)d_in[14];
    const float* cb3 = (const float*)d_in[15];
    float* out = (float*)d_out;
    char* ws = (char*)d_ws;

    // workspace layout (bytes)
    float*          x4 = (float*)(ws + 0);                       // 4096*4096*4  = 64 MB
    __hip_bfloat16* t1 = (__hip_bfloat16*)(ws + 67108864);       // 4096*128*64*2 = 64 MB
    __hip_bfloat16* t2 = (__hip_bfloat16*)(ws + 134217728);      // 4096*256*64*2 = 128 MB
    float*          x1 = (float*)(ws + 268435456);               // 1 MB
    float*          x2 = (float*)(ws + 269484032);               // 4 MB
    float*          x3 = (float*)(ws + 273678336);               // 16 MB
    float*          stats = (float*)(ws + 290455552);            // 32 KB
    // total ~277 MB

    dim3 blk(256);

    // MLP stack
    gemm_leaky_kernel<<<dim3(1, 64),  blk, 0, stream>>>(trees, W1, b1, x1, B, 64, 16);
    gemm_leaky_kernel<<<dim3(4, 64),  blk, 0, stream>>>(x1, W2, b2, x2, B, 256, 64);
    gemm_leaky_kernel<<<dim3(16, 64), blk, 0, stream>>>(x2, W3, b3, x3, B, 1024, 256);
    gemm_leaky_kernel<<<dim3(64, 64), blk, 0, stream>>>(x3, W4, b4, x4, B, 4096, 1024);

    // conv1: C=64 -> O=128 (input x4 fp32, output t1 bf16)
    zero_kernel<<<32, blk, 0, stream>>>(stats, 2 * B);
    conv_kernel<64, 128, float, __hip_bfloat16>
        <<<dim3(2, B), blk, 0, stream>>>(x4, indexes, cw1, cb1, t1, stats);
    ln_leaky_kernel<__hip_bfloat16>
        <<<(B * 128LL * 64 + 255) / 256, blk, 0, stream>>>(t1, stats, 128 * 64, (long long)B * 128 * 64);

    // conv2: C=128 -> O=256
    zero_kernel<<<32, blk, 0, stream>>>(stats, 2 * B);
    conv_kernel<128, 256, __hip_bfloat16, __hip_bfloat16>
        <<<dim3(4, B), blk, 0, stream>>>(t1, indexes, cw2, cb2, t2, stats);
    ln_leaky_kernel<__hip_bfloat16>
        <<<(B * 256LL * 64 + 255) / 256, blk, 0, stream>>>(t2, stats, 256 * 64, (long long)B * 256 * 64);

    // conv3: C=256 -> O=512 (raw fp32 straight into d_out, LN in-place)
    zero_kernel<<<32, blk, 0, stream>>>(stats, 2 * B);
    conv_kernel<256, 512, __hip_bfloat16, float>
        <<<dim3(8, B), blk, 0, stream>>>(t2, indexes, cw3, cb3, out, stats);
    ln_leaky_kernel<float>
        <<<(B * 512LL * 64 + 255) / 256, blk, 0, stream>>>(out, stats, 512 * 64, (long long)B * 512 * 64);
}